// Round 5
// baseline (636.792 us; speedup 1.0000x reference)
//
#include <hip/hip_runtime.h>
#include <hip/hip_bf16.h>
#include <hip/hip_fp16.h>
#include <math.h>

#define NV 32000
#define NE 50
#define NH 100
#define NB 8
#define NT 512
#define KP 112    // K padded to 7 k-tiles of 16 for outgemm mfma_32x32x16
#define HS 136    // h16/rh16 LDS row stride in fp16 (272 B: 2-way bank max)

typedef __attribute__((ext_vector_type(8)))  _Float16 f16x8;
typedef __attribute__((ext_vector_type(4)))  float    f32x4;
typedef __attribute__((ext_vector_type(16))) float    f32x16;

// LDS-only barrier, race-free (R3): pre-barrier clobber+lgkmcnt pins LDS writes
// before the rendezvous; post-barrier clobber pins reads after. Global loads/
// stores (vmcnt) stay in flight across it.
__device__ __forceinline__ void bar_lgkm() {
    __builtin_amdgcn_sched_barrier(0);
    asm volatile("s_waitcnt lgkmcnt(0)" ::: "memory");
    __builtin_amdgcn_s_barrier();
    asm volatile("" ::: "memory");
    __builtin_amdgcn_sched_barrier(0);
}

// ---------------------------------------------------------------------------
// Kernel 0a: fc_W f32 [k][v] -> fp16 MFMA-B-frag order (32x32x16), unchanged R4.
// ---------------------------------------------------------------------------
__global__ __launch_bounds__(256) void convw_kernel(
    const float* __restrict__ W, _Float16* __restrict__ Wp)
{
    int wv = threadIdx.x >> 6, l = threadIdx.x & 63;
    int ct = blockIdx.x * 4 + wv;
    int v  = ct * 32 + (l & 31);
    int kb = (l >> 5) * 8;
    _Float16* dst = Wp + (size_t)ct * 7 * 512 + l * 8;
    for (int kt = 0; kt < 7; kt++) {
        f16x8 tmp;
        #pragma unroll
        for (int j = 0; j < 8; j++) {
            int k = kt * 16 + kb + j;
            tmp[j] = (_Float16)(k < NH ? W[(size_t)k * NV + v] : 0.0f);
        }
        *(f16x8*)(dst + (size_t)kt * 512) = tmp;
    }
}

// ---------------------------------------------------------------------------
// Kernel 0b: gate weights -> fp16 B-frags for mfma_f32_16x16x32_f16.
// frag index f = (g*7 + n)*4 + kt ; lane l holds col n*16+(l&15),
// k = kt*32 + (l>>4)*8 + j  (zero outside 100x100).
// ---------------------------------------------------------------------------
__global__ __launch_bounds__(64) void convg_kernel(
    const float* __restrict__ Whr, const float* __restrict__ Whz,
    const float* __restrict__ Whh, _Float16* __restrict__ Wg)
{
    int f = blockIdx.x;                 // 0..83
    int g = f / 28, rem = f % 28, n = rem / 4, kt = rem % 4;
    const float* W = (g == 0) ? Whr : (g == 1) ? Whz : Whh;
    int l   = threadIdx.x;
    int col = n * 16 + (l & 15);
    int k0  = kt * 32 + (l >> 4) * 8;
    f16x8 v;
    #pragma unroll
    for (int j = 0; j < 8; j++) {
        int k = k0 + j;
        v[j] = (_Float16)((k < NH && col < NH) ? W[k * NH + col] : 0.0f);
    }
    *(f16x8*)(Wg + (size_t)f * 512 + l * 8) = v;
}

// ---------------------------------------------------------------------------
// Kernel 1: embed + input projections (unchanged).
// ---------------------------------------------------------------------------
__global__ __launch_bounds__(128) void xproj_kernel(
    const int* __restrict__ inp, const float* __restrict__ emb,
    const float* __restrict__ Wxr, const float* __restrict__ br,
    const float* __restrict__ Wxz, const float* __restrict__ bz,
    const float* __restrict__ Wxh, const float* __restrict__ bh,
    float* __restrict__ Xr, float* __restrict__ Xz, float* __restrict__ Xh)
{
    int n = blockIdx.x;            // n = t*NB + b
    int t = n >> 3, b = n & 7;
    __shared__ float xs[NE];
    int tid = threadIdx.x;
    int idx = inp[b * NT + t];
    if (tid < NE) xs[tid] = emb[idx * NE + tid];
    __syncthreads();
    if (tid < NH) {
        float ar = br[tid], az = bz[tid], ah = bh[tid];
        for (int e = 0; e < NE; e++) {
            float x = xs[e];
            ar += x * Wxr[e * NH + tid];
            az += x * Wxz[e * NH + tid];
            ah += x * Wxh[e * NH + tid];
        }
        Xr[n * NH + tid] = ar;
        Xz[n * NH + tid] = az;
        Xh[n * NH + tid] = ah;
    }
}

// ---------------------------------------------------------------------------
// Kernel 2: MFMA GRU recurrence. One block per batch, 4 waves (1/SIMD).
// Wave w owns n-tiles {w, w+4}; holds R/Z/H B-frags in regs; h,z in-lane
// (D col = lane = j). LDS only bounces h/rh fp16 A-frags. 2 bar_lgkm/step.
// ---------------------------------------------------------------------------
__global__ __launch_bounds__(256) void gru_rec_kernel(
    const _Float16* __restrict__ Wg,
    const float* __restrict__ Xr, const float* __restrict__ Xz,
    const float* __restrict__ Xh, _Float16* __restrict__ Hp)
{
    int b   = blockIdx.x;
    int tid = threadIdx.x;
    int w   = tid >> 6, l = tid & 63;
    int lj  = l & 15;

    __shared__ __align__(16) _Float16 h16[16 * HS];
    __shared__ __align__(16) _Float16 rh16[16 * HS];
    for (int i = tid; i < 16 * HS; i += 256) { h16[i] = (_Float16)0.0f; rh16[i] = (_Float16)0.0f; }
    __syncthreads();

    int n0 = w, n1 = w + 4;
    bool has1 = (n1 < 7);
    int n1c = has1 ? n1 : n0;

    // B-fragments (g,n,kt) -> Wg[((g*7+n)*4+kt)*512 + l*8]
    f16x8 WR0[4], WZ0[4], WH0[4], WR1[4], WZ1[4], WH1[4];
    #pragma unroll
    for (int kt = 0; kt < 4; kt++) {
        WR0[kt] = *(const f16x8*)(Wg + (size_t)(((0*7 + n0)*4 + kt))*512 + l*8);
        WZ0[kt] = *(const f16x8*)(Wg + (size_t)(((1*7 + n0)*4 + kt))*512 + l*8);
        WH0[kt] = *(const f16x8*)(Wg + (size_t)(((2*7 + n0)*4 + kt))*512 + l*8);
        WR1[kt] = *(const f16x8*)(Wg + (size_t)(((0*7 + n1c)*4 + kt))*512 + l*8);
        WZ1[kt] = *(const f16x8*)(Wg + (size_t)(((1*7 + n1c)*4 + kt))*512 + l*8);
        WH1[kt] = *(const f16x8*)(Wg + (size_t)(((2*7 + n1c)*4 + kt))*512 + l*8);
    }

    int j0 = n0 * 16 + lj;                 // this lane's output index, tile 0
    int j1 = n1c * 16 + lj;                // tile 1
    int j0x = j0 < NH ? j0 : NH - 1;       // clamped x addr (OOB-safe)
    int j1x = j1 < NH ? j1 : NH - 1;

    float h0 = 0.0f, h1 = 0.0f;
    float xr0, xz0, xh0, xr1, xz1, xh1;
    if (l < 16) {
        int base = b * NH;
        xr0 = Xr[base + j0x]; xz0 = Xz[base + j0x]; xh0 = Xh[base + j0x];
        xr1 = Xr[base + j1x]; xz1 = Xz[base + j1x]; xh1 = Xh[base + j1x];
    }

    int aoff = lj * HS + (l >> 4) * 8;     // A-frag base (row l&15, k-group l>>4)

    for (int t = 0; t < NT; t++) {
        // prefetch x for t+1 (stays in flight across bar_lgkm)
        float pr0, pz0, ph0, pr1, pz1, ph1;
        if (l < 16 && t + 1 < NT) {
            int base = ((t + 1) * NB + b) * NH;
            pr0 = Xr[base + j0x]; pz0 = Xz[base + j0x]; ph0 = Xh[base + j0x];
            pr1 = Xr[base + j1x]; pz1 = Xz[base + j1x]; ph1 = Xh[base + j1x];
        }

        // ---- phase 1: R,Z = sigmoid(h @ W + x) ----
        f32x4 aR0 = {0,0,0,0}, aZ0 = {0,0,0,0}, aR1 = {0,0,0,0}, aZ1 = {0,0,0,0};
        #pragma unroll
        for (int kt = 0; kt < 4; kt++) {
            f16x8 a = *(const f16x8*)&h16[aoff + kt * 32];
            aR0 = __builtin_amdgcn_mfma_f32_16x16x32_f16(a, WR0[kt], aR0, 0, 0, 0);
            aZ0 = __builtin_amdgcn_mfma_f32_16x16x32_f16(a, WZ0[kt], aZ0, 0, 0, 0);
            aR1 = __builtin_amdgcn_mfma_f32_16x16x32_f16(a, WR1[kt], aR1, 0, 0, 0);
            aZ1 = __builtin_amdgcn_mfma_f32_16x16x32_f16(a, WZ1[kt], aZ1, 0, 0, 0);
        }
        float z0 = 0.0f, z1 = 0.0f;
        if (l < 16) {
            float r0 = 1.0f / (1.0f + __expf(-(aR0[0] + xr0)));
            z0       = 1.0f / (1.0f + __expf(-(aZ0[0] + xz0)));
            rh16[j0] = (_Float16)(j0 < NH ? r0 * h0 : 0.0f);
            if (has1) {
                float r1 = 1.0f / (1.0f + __expf(-(aR1[0] + xr1)));
                z1       = 1.0f / (1.0f + __expf(-(aZ1[0] + xz1)));
                rh16[j1] = (_Float16)(j1 < NH ? r1 * h1 : 0.0f);
            }
        }
        bar_lgkm();                         // rh16 visible

        // ---- phase 2: Htilda = tanh(rh @ Whh + x); h update ----
        f32x4 aH0 = {0,0,0,0}, aH1 = {0,0,0,0};
        #pragma unroll
        for (int kt = 0; kt < 4; kt++) {
            f16x8 a = *(const f16x8*)&rh16[aoff + kt * 32];
            aH0 = __builtin_amdgcn_mfma_f32_16x16x32_f16(a, WH0[kt], aH0, 0, 0, 0);
            aH1 = __builtin_amdgcn_mfma_f32_16x16x32_f16(a, WH1[kt], aH1, 0, 0, 0);
        }
        if (l < 16) {
            size_t hpb = (size_t)(t * NB + b) * KP;
            {
                float e  = __expf(2.0f * (aH0[0] + xh0));
                float ht = 1.0f - 2.0f / (e + 1.0f);
                float hn = fmaf(z0, ht - h0, h0);
                hn = (j0 < NH) ? hn : 0.0f;
                h0 = hn;
                h16[j0] = (_Float16)hn;
                Hp[hpb + j0] = (_Float16)hn;
            }
            if (has1) {
                float e  = __expf(2.0f * (aH1[0] + xh1));
                float ht = 1.0f - 2.0f / (e + 1.0f);
                float hn = fmaf(z1, ht - h1, h1);
                hn = (j1 < NH) ? hn : 0.0f;
                h1 = hn;
                h16[j1] = (_Float16)hn;
                Hp[hpb + j1] = (_Float16)hn;
            }
        }
        bar_lgkm();                         // h16 visible for next step

        xr0 = pr0; xz0 = pz0; xh0 = ph0;
        xr1 = pr1; xz1 = pz1; xh1 = ph1;
    }
}

// ---------------------------------------------------------------------------
// Kernel 3: out-GEMM via fp16 MFMA (unchanged R4, verified).
// ---------------------------------------------------------------------------
__global__ __launch_bounds__(256) void outgemm_kernel(
    const _Float16* __restrict__ Hp, const _Float16* __restrict__ Wp,
    const float* __restrict__ fcb, float* __restrict__ out)
{
    int tid = threadIdx.x;
    int wv = tid >> 6, l = tid & 63;
    int n0 = blockIdx.x * 32;
    int cb = blockIdx.y * 256 + wv * 64;

    const _Float16* arow = Hp + (size_t)(n0 + (l & 31)) * KP + (l >> 5) * 8;
    f16x8 a[7];
    #pragma unroll
    for (int kt = 0; kt < 7; kt++)
        a[kt] = *(const f16x8*)(arow + kt * 16);

    int ct0 = cb >> 5;
    const _Float16* bp = Wp + (size_t)ct0 * 7 * 512 + l * 8;

    f32x16 acc0 = {0,0,0,0,0,0,0,0,0,0,0,0,0,0,0,0};
    f32x16 acc1 = {0,0,0,0,0,0,0,0,0,0,0,0,0,0,0,0};
    #pragma unroll
    for (int kt = 0; kt < 7; kt++) {
        f16x8 b0 = *(const f16x8*)(bp + (size_t)kt * 512);
        f16x8 b1 = *(const f16x8*)(bp + (size_t)(kt + 7) * 512);
        acc0 = __builtin_amdgcn_mfma_f32_32x32x16_f16(a[kt], b0, acc0, 0, 0, 0);
        acc1 = __builtin_amdgcn_mfma_f32_32x32x16_f16(a[kt], b1, acc1, 0, 0, 0);
    }

    int c0 = cb + (l & 31);
    float bias0 = fcb[c0], bias1 = fcb[c0 + 32];
    #pragma unroll
    for (int p = 0; p < 16; p++) {
        int r = (p & 3) + 8 * (p >> 2) + 4 * (l >> 5);
        int m = n0 + r;
        size_t row = (size_t)(m & 7) * NT + (m >> 3);   // b*512 + t
        out[row * NV + c0]      = acc0[p] + bias0;
        out[row * NV + c0 + 32] = acc1[p] + bias1;
    }
}

// ---------------------------------------------------------------------------
extern "C" void kernel_launch(void* const* d_in, const int* in_sizes, int n_in,
                              void* d_out, int out_size, void* d_ws, size_t ws_size,
                              hipStream_t stream)
{
    const int*   inp = (const int*)  d_in[0];
    const float* emb = (const float*)d_in[1];
    const float* Whr = (const float*)d_in[2];
    const float* Wxr = (const float*)d_in[3];
    const float* br  = (const float*)d_in[4];
    const float* Whz = (const float*)d_in[5];
    const float* Wxz = (const float*)d_in[6];
    const float* bz  = (const float*)d_in[7];
    const float* Whh = (const float*)d_in[8];
    const float* Wxh = (const float*)d_in[9];
    const float* bh  = (const float*)d_in[10];
    const float* fcW = (const float*)d_in[11];
    const float* fcb = (const float*)d_in[12];
    float* out = (float*)d_out;

    float*    Xr = (float*)d_ws;                       // [NT*NB*NH] f32
    float*    Xz = Xr + NT * NB * NH;
    float*    Xh = Xz + NT * NB * NH;
    _Float16* Hp = (_Float16*)(Xh + NT * NB * NH);     // [NT*NB][KP] fp16
    _Float16* Wp = Hp + (size_t)NT * NB * KP;          // [1000*7*512] fp16
    _Float16* Wg = Wp + (size_t)1000 * 7 * 512;        // [84*512] fp16

    convw_kernel<<<NV / 32 / 4, 256, 0, stream>>>(fcW, Wp);
    convg_kernel<<<84, 64, 0, stream>>>(Whr, Whz, Whh, Wg);
    xproj_kernel<<<NT * NB, 128, 0, stream>>>(inp, emb, Wxr, br, Wxz, bz, Wxh, bh,
                                              Xr, Xz, Xh);
    gru_rec_kernel<<<NB, 256, 0, stream>>>(Wg, Xr, Xz, Xh, Hp);
    dim3 ggrid(NT * NB / 32, NV / 256);
    outgemm_kernel<<<ggrid, 256, 0, stream>>>(Hp, Wp, fcb, out);
}